// Round 8
// baseline (89.876 us; speedup 1.0000x reference)
//
#include <hip/hip_runtime.h>
#include <math.h>

// Problem constants (match reference)
#define B_  4
#define C_  128
#define H_  240
#define W_  320
#define N_  1024
#define NPTS (B_ * N_)          // 4096
#define HW_ (H_ * W_)
#define NBINS 960               // key = b*240 + y0
#define SH    20                // y0 rows per slab
#define NSLB  12                // 240 / 20 slabs per plane
#define BROWS 23                // SH + 3 halo rows (y0-1 .. y0+2)
#define BF4   ((BROWS * W_) / 4)// 1840 f4 slots in the LDS buffer
#define NFA   1024              // F_a random-gather blocks (dispatched first)
#define NFBK  512               // F_b persistent streaming blocks (b, c)

typedef float f4 __attribute__((ext_vector_type(4)));
typedef float f2 __attribute__((ext_vector_type(2)));

__device__ __forceinline__ f4 load4(const float* p) {
    f4 v; __builtin_memcpy(&v, p, 16); return v;
}
__device__ __forceinline__ f2 load2(const float* p) {
    f2 v; __builtin_memcpy(&v, p, 8); return v;
}

// ---------------------------------------------------------------------------
// Kernel 0: counting-sorts + packed slot tables.
//  pass 1 (F_b sample row): permB, binStart, xsys[slot]=(xs,ys),
//                           ubuv[slot]=(ubx,uby)
//  pass 2 (F_a sample row): xaya[slotA]=(xa,ya), a2b[slotA]=(b<<16)|slotB
// Slot assignment within a bin is atomic-race nondeterministic, but every
// per-point value downstream is a pure function of the point id, and final
// per-point results are written p-indexed -> output bitwise deterministic.
// ---------------------------------------------------------------------------
__global__ __launch_bounds__(1024) void gn_sort_kernel(
    const float* __restrict__ ma, const float* __restrict__ mb,
    const float* __restrict__ noise,
    int* __restrict__ permB, int* __restrict__ binStart,
    float* __restrict__ xsys, float* __restrict__ ubuv,
    float* __restrict__ xaya, int* __restrict__ a2b)
{
    __shared__ int hist[NBINS];
    __shared__ int cursor[NBINS];

    // ---------------- pass 1: F_b ----------------
    for (int i = threadIdx.x; i < NBINS; i += 1024) hist[i] = 0;
    __syncthreads();
    int keyB[4], slotB[4];
    float vxs[4], vys[4], vux[4], vuy[4];
    #pragma unroll
    for (int k = 0; k < 4; ++k) {
        const int p = threadIdx.x + (k << 10);
        const float ubx = mb[p * 2 + 0] * 0.125f;
        const float uby = mb[p * 2 + 1] * 0.125f;
        const float xs  = 2.0f * noise[p * 2 + 0] - 1.0f + ubx;
        const float ys  = 2.0f * noise[p * 2 + 1] - 1.0f + uby;
        const int y0 = min(max((int)floorf(ys), 1), H_ - 3);
        keyB[k] = (p >> 10) * H_ + y0;
        vxs[k] = xs; vys[k] = ys; vux[k] = ubx; vuy[k] = uby;
        atomicAdd(&hist[keyB[k]], 1);
    }
    __syncthreads();
    if (threadIdx.x < 64) {
        const int lane = threadIdx.x;
        const int base = lane * 15;
        int loc[15]; int s = 0;
        #pragma unroll
        for (int i = 0; i < 15; ++i) { loc[i] = s; s += hist[base + i]; }
        int incl = s;
        #pragma unroll
        for (int off = 1; off < 64; off <<= 1) {
            const int v = __shfl_up(incl, off, 64);
            if (lane >= off) incl += v;
        }
        const int excl = incl - s;
        #pragma unroll
        for (int i = 0; i < 15; ++i) cursor[base + i] = excl + loc[i];
    }
    __syncthreads();
    for (int i = threadIdx.x; i < NBINS; i += 1024) binStart[i] = cursor[i];
    if (threadIdx.x == 0) binStart[NBINS] = NPTS;
    __syncthreads();
    #pragma unroll
    for (int k = 0; k < 4; ++k) {
        const int p = threadIdx.x + (k << 10);
        const int pos = atomicAdd(&cursor[keyB[k]], 1);
        permB[pos] = p;
        xsys[2 * pos]     = vxs[k];
        xsys[2 * pos + 1] = vys[k];
        ubuv[2 * pos]     = vux[k];
        ubuv[2 * pos + 1] = vuy[k];
        slotB[k] = pos;
    }
    __syncthreads();

    // ---------------- pass 2: F_a ----------------
    for (int i = threadIdx.x; i < NBINS; i += 1024) hist[i] = 0;
    __syncthreads();
    int keyA[4];
    float vxa[4], vya[4];
    #pragma unroll
    for (int k = 0; k < 4; ++k) {
        const int p = threadIdx.x + (k << 10);
        const float xa = ma[p * 2 + 0] * 0.125f;
        const float ya = ma[p * 2 + 1] * 0.125f;
        const int ay0 = min(max((int)floorf(ya), 0), H_ - 2);
        keyA[k] = (p >> 10) * H_ + ay0;
        vxa[k] = xa; vya[k] = ya;
        atomicAdd(&hist[keyA[k]], 1);
    }
    __syncthreads();
    if (threadIdx.x < 64) {
        const int lane = threadIdx.x;
        const int base = lane * 15;
        int loc[15]; int s = 0;
        #pragma unroll
        for (int i = 0; i < 15; ++i) { loc[i] = s; s += hist[base + i]; }
        int incl = s;
        #pragma unroll
        for (int off = 1; off < 64; off <<= 1) {
            const int v = __shfl_up(incl, off, 64);
            if (lane >= off) incl += v;
        }
        const int excl = incl - s;
        #pragma unroll
        for (int i = 0; i < 15; ++i) cursor[base + i] = excl + loc[i];
    }
    __syncthreads();
    #pragma unroll
    for (int k = 0; k < 4; ++k) {
        const int p = threadIdx.x + (k << 10);
        const int pos = atomicAdd(&cursor[keyA[k]], 1);
        xaya[2 * pos]     = vxa[k];
        xaya[2 * pos + 1] = vya[k];
        a2b[pos] = ((p >> 10) << 16) | slotB[k];
    }
}

// ---------------------------------------------------------------------------
// Kernel 1 (fused):
//  bid <  NFA : F_a random gather. wave = (point-group, channel pair);
//               reads xaya/a2b coalesced; writes ws_ft[c][slotB].
//  bid >= NFA : F_b persistent plane stream. block = (b, c). 12 slabs of 20
//               y0-rows, single 23-row LDS buffer, T14 async split:
//               ds_write(tmp of slab t) -> barrier -> ISSUE(slab t+1, no wait)
//               -> COMPUTE(slab t) -> barrier. HBM latency hides under compute.
// ---------------------------------------------------------------------------
__global__ __launch_bounds__(256) void gn_main_kernel(
    const float* __restrict__ Fa, const float* __restrict__ Fb,
    const int* __restrict__ binStart,
    const float* __restrict__ xsys, const float* __restrict__ xaya,
    const int* __restrict__ a2b,
    float* __restrict__ ws_ft, float* __restrict__ fjp)
{
    __shared__ float buf[BROWS * W_];   // 29440 B
    const int tid = threadIdx.x;
    const int bid = blockIdx.x;

    if (bid < NFA) {
        // ---------------- F_a random-gather path ----------------
        const int w    = (bid << 2) | (tid >> 6);     // wave 0..4095
        const int lane = tid & 63;
        const int pg   = w >> 6;                      // point group 0..63
        const int c0   = (w & 63) << 1;               // channels c0, c0+1
        const int ai   = (pg << 6) | lane;            // A-slot (sorted by ya)

        const f2 xy   = load2(xaya + 2 * ai);
        const int meta = a2b[ai];
        const int b     = meta >> 16;
        const int slotB = meta & 0xFFFF;

        const float xa = xy.x, ya = xy.y;
        const float ax0f = floorf(xa), ay0f = floorf(ya);
        const float awx = xa - ax0f, awy = ya - ay0f;
        const int ax0 = min(max((int)ax0f, 0), W_ - 2);
        const int ay0 = min(max((int)ay0f, 0), H_ - 2);
        const int o0 = ay0 * W_ + ax0;
        const int o1 = o0 + W_;

        const float* __restrict__ fa0 = Fa + ((size_t)(b * C_ + c0)) * HW_;
        const float* __restrict__ fa1 = fa0 + HW_;

        const f2 a0_0 = load2(fa0 + o0);
        const f2 a1_0 = load2(fa0 + o1);
        const f2 a0_1 = load2(fa1 + o0);
        const f2 a1_1 = load2(fa1 + o1);

        const float w00 = (1.f - awx) * (1.f - awy);
        const float w01 = awx * (1.f - awy);
        const float w10 = (1.f - awx) * awy;
        const float w11 = awx * awy;

        const float ft0 = a0_0.x * w00 + a0_0.y * w01 + a1_0.x * w10 + a1_0.y * w11;
        const float ft1 = a0_1.x * w00 + a0_1.y * w01 + a1_1.x * w10 + a1_1.y * w11;

        ws_ft[(size_t)c0 * NPTS + slotB]       = ft0;
        ws_ft[(size_t)(c0 + 1) * NPTS + slotB] = ft1;
    } else {
        // ---------------- F_b persistent streaming path ----------------
        const int blk = bid - NFA;            // 0..511
        const int c = blk & (C_ - 1);
        const int b = blk >> 7;
        const float* __restrict__ plane = Fb + ((size_t)(b * C_ + c)) * HW_;

        f4 tmp[8];
        // prologue: issue slab 0 (rows -1..21)
        {
            const int sbase = -W_;
            #pragma unroll
            for (int k = 0; k < 8; ++k) {
                int src = sbase + ((tid + (k << 8)) << 2);
                src = min(max(src, 0), HW_ - 4);
                tmp[k] = load4(plane + src);
            }
        }

        for (int t = 0; t < NSLB; ++t) {
            // drain slab-t loads (issued one compute-phase ago) into LDS
            #pragma unroll
            for (int k = 0; k < 8; ++k) {
                const int slot = tid + (k << 8);
                if (slot < BF4) *(f4*)&buf[slot << 2] = tmp[k];
            }
            __syncthreads();

            // issue slab t+1 loads -- NO wait; latency hides under compute
            if (t + 1 < NSLB) {
                const int sbase = ((t + 1) * SH - 1) * W_;
                #pragma unroll
                for (int k = 0; k < 8; ++k) {
                    int src = sbase + ((tid + (k << 8)) << 2);
                    src = min(max(src, 0), HW_ - 4);
                    tmp[k] = load4(plane + src);
                }
            }

            // compute slab t: points with y0 in [SH*t, SH*t+SH)
            const int binbase = b * H_ + t * SH;
            const int pLo = binStart[binbase];
            const int pHi = binStart[binbase + SH];
            const int ybase = t * SH - 1;     // image row of LDS row 0

            for (int i = pLo + tid; i < pHi; i += 256) {
                const f2 sc = load2(xsys + 2 * i);
                const float xs = sc.x, ys = sc.y;
                const float bx0f = floorf(xs), by0f = floorf(ys);
                const float wx = xs - bx0f, wy = ys - by0f;
                const int x0 = min(max((int)bx0f, 1), W_ - 3);
                const int y0 = min(max((int)by0f, 1), H_ - 3);
                const int rel = y0 - ybase;                  // 1..20

                const float* rY0 = &buf[rel * W_];
                const float* rY1 = rY0 + W_;
                const float* rYm = rY0 - W_;
                const float* rYp = rY1 + W_;

                const float r0m = rY0[x0 - 1], r00 = rY0[x0];
                const float r01 = rY0[x0 + 1], r0p = rY0[x0 + 2];
                const float r1m = rY1[x0 - 1], r10 = rY1[x0];
                const float r11 = rY1[x0 + 1], r1p = rY1[x0 + 2];
                const float rm0 = rYm[x0],     rm1 = rYm[x0 + 1];
                const float rp0 = rYp[x0],     rp1 = rYp[x0 + 1];

                const float w00 = (1.f - wx) * (1.f - wy);
                const float w01 = wx * (1.f - wy);
                const float w10 = (1.f - wx) * wy;
                const float w11 = wx * wy;

                const float fs = r00 * w00 + r01 * w01 + r10 * w10 + r11 * w11;
                const float jx = 0.5f * ((r01 - r0m) * w00 + (r0p - r00) * w01
                                       + (r11 - r1m) * w10 + (r1p - r10) * w11);
                const float jy = 0.5f * ((r10 - rm0) * w00 + (r11 - rm1) * w01
                                       + (rp0 - r00) * w10 + (rp1 - r01) * w11);

                const size_t base = (size_t)c * 3 * NPTS + i;   // slot-major
                fjp[base]            = fs;
                fjp[base + NPTS]     = jx;
                fjp[base + 2 * NPTS] = jy;
            }
            __syncthreads();
        }
    }
}

// ---------------------------------------------------------------------------
// Kernel 2: per-point channel reduction (fixed order c=0..127) + 2x2 GN solve.
// thread = slot; all reads fully coalesced; result written p-indexed.
// ---------------------------------------------------------------------------
__global__ __launch_bounds__(64) void gn_combine_kernel(
    const float* __restrict__ ws_ft, const float* __restrict__ fjp,
    const float* __restrict__ xsys, const float* __restrict__ ubuv,
    const int* __restrict__ permB,
    float* __restrict__ ws_e1, float* __restrict__ ws_ld)
{
    const int i = blockIdx.x * 64 + threadIdx.x;   // slot

    float s[9];
    #pragma unroll
    for (int k = 0; k < 9; ++k) s[k] = 0.f;

    #pragma unroll 4
    for (int c = 0; c < C_; ++c) {
        const float ft = ws_ft[(size_t)c * NPTS + i];
        const size_t base = (size_t)c * 3 * NPTS + i;
        const float fs = fjp[base];
        const float jx = fjp[base + NPTS];
        const float jy = fjp[base + 2 * NPTS];
        s[0] += ft * ft;
        s[1] += fs * fs;
        s[2] += jx * fs;
        s[3] += jx * ft;
        s[4] += jy * fs;
        s[5] += jy * ft;
        s[6] += jx * jx;
        s[7] += jx * jy;
        s[8] += jy * jy;
    }

    const f2 uu = load2(ubuv + 2 * i);
    const f2 sc = load2(xsys + 2 * i);
    const float ubx = uu.x, uby = uu.y;
    const float xs = sc.x, ys = sc.y;

    const float nt = fmaxf(sqrtf(s[0]), 1e-12f);
    const float ns = fmaxf(sqrtf(s[1]), 1e-12f);
    const float b0 = s[2] / ns - s[3] / nt;
    const float b1 = s[4] / ns - s[5] / nt;
    const float H00 = s[6] + 1e-9f;
    const float H01 = s[7];
    const float H11 = s[8] + 1e-9f;
    const float det = H00 * H11 - H01 * H01;
    const float inv = 1.0f / det;
    const float u0 = (H11 * b0 - H01 * b1) * inv;
    const float u1 = (H00 * b1 - H01 * b0) * inv;
    const float d0 = (ubx - xs) + u0;
    const float d1 = (uby - ys) + u1;
    const float quad = d0 * (H00 * d0 + H01 * d1) + d1 * (H01 * d0 + H11 * d1);

    const int p = permB[i];
    ws_e1[p] = 0.5f * quad;
    ws_ld[p] = logf(det);
}

// ---------------------------------------------------------------------------
// Kernel 3: single-block deterministic reduction of the 4096 partials.
// ---------------------------------------------------------------------------
__global__ __launch_bounds__(256) void gn_reduce_kernel(
    const float* __restrict__ ws_e1, const float* __restrict__ ws_ld,
    float* __restrict__ out)
{
    __shared__ double sm1[256];
    __shared__ double sm2[256];
    double a1 = 0.0, a2 = 0.0;
    for (int i = threadIdx.x; i < NPTS; i += 256) {
        a1 += (double)ws_e1[i];
        a2 += (double)ws_ld[i];
    }
    sm1[threadIdx.x] = a1;
    sm2[threadIdx.x] = a2;
    __syncthreads();
    for (int s = 128; s > 0; s >>= 1) {
        if (threadIdx.x < s) {
            sm1[threadIdx.x] += sm1[threadIdx.x + s];
            sm2[threadIdx.x] += sm2[threadIdx.x + s];
        }
        __syncthreads();
    }
    if (threadIdx.x == 0) {
        const double e1 = sm1[0];
        const double sum_ld = sm2[0];
        const double log2pi = (double)logf(6.283185307179586f);
        const double e2 = (double)NPTS * log2pi - 0.5 * sum_ld;
        const double e = 1.0 * e1 + (2.0 / 7.0) * e2;   // E1_LAMDA=1, E2_LAMDA=2/7
        out[0] = (float)(0.3 * e);                      // GN_LAMDA * e
        out[1] = (float)e1;
        out[2] = (float)e2;
    }
}

extern "C" void kernel_launch(void* const* d_in, const int* in_sizes, int n_in,
                              void* d_out, int out_size, void* d_ws, size_t ws_size,
                              hipStream_t stream) {
    const float* Fa    = (const float*)d_in[0];
    const float* Fb    = (const float*)d_in[1];
    const float* ma    = (const float*)d_in[2];
    const float* mb    = (const float*)d_in[3];
    const float* noise = (const float*)d_in[4];
    float* out = (float*)d_out;

    float* ws_e1    = (float*)d_ws;                 // 4096
    float* ws_ld    = ws_e1 + NPTS;                 // 4096
    int*   permB    = (int*)(ws_ld + NPTS);         // 4096
    int*   binStart = permB + NPTS;                 // 1024 (961 used)
    int*   a2b      = binStart + 1024;              // 4096
    float* xsys     = (float*)(a2b + NPTS);         // 8192
    float* ubuv     = xsys + 2 * NPTS;              // 8192
    float* xaya     = ubuv + 2 * NPTS;              // 8192
    float* ws_ft    = xaya + 2 * NPTS;              // 128*4096   (2 MiB)
    float* fjp      = ws_ft + (size_t)C_ * NPTS;    // 128*3*4096 (6 MiB)

    gn_sort_kernel<<<1, 1024, 0, stream>>>(ma, mb, noise, permB, binStart,
                                           xsys, ubuv, xaya, a2b);
    gn_main_kernel<<<NFA + NFBK, 256, 0, stream>>>(Fa, Fb, binStart,
                                                   xsys, xaya, a2b,
                                                   ws_ft, fjp);
    gn_combine_kernel<<<NPTS / 64, 64, 0, stream>>>(ws_ft, fjp, xsys, ubuv,
                                                    permB, ws_e1, ws_ld);
    gn_reduce_kernel<<<1, 256, 0, stream>>>(ws_e1, ws_ld, out);
}

// Round 9
// 70.295 us; speedup vs baseline: 1.2786x; 1.2786x over previous
//
#include <hip/hip_runtime.h>
#include <math.h>

// Problem constants (match reference)
#define B_  4
#define C_  128
#define H_  240
#define W_  320
#define N_  1024
#define NPTS (B_ * N_)          // 4096
#define HW_ (H_ * W_)

typedef float f4 __attribute__((ext_vector_type(4)));
typedef float f2 __attribute__((ext_vector_type(2)));

__device__ __forceinline__ f4 load4(const float* p) {
    f4 v;
    __builtin_memcpy(&v, p, 16);   // align-4 dwordx4
    return v;
}
__device__ __forceinline__ f2 load2(const float* p) {
    f2 v;
    __builtin_memcpy(&v, p, 8);    // align-4 dwordx2
    return v;
}

__device__ __forceinline__ float wave_reduce(float v) {
    #pragma unroll
    for (int off = 32; off > 0; off >>= 1)
        v += __shfl_xor(v, off, 64);
    return v;
}

// One WAVE per point; lane l owns channels l and l+64.
// 256-thread blocks = 4 points per block, no LDS, no __syncthreads.
__global__ __launch_bounds__(256) void gn_point_kernel(
    const float* __restrict__ Fa, const float* __restrict__ Fb,
    const float* __restrict__ ma, const float* __restrict__ mb,
    const float* __restrict__ noise,
    float* __restrict__ ws_e1, float* __restrict__ ws_ld)
{
    const int wid  = threadIdx.x >> 6;        // wave in block (0..3)
    const int lane = threadIdx.x & 63;
    const int p = (blockIdx.x << 2) | wid;    // point 0..4095
    const int b = p >> 10;                    // batch

    const float inv_level = 0.125f;
    const float xa  = ma[p * 2 + 0] * inv_level;
    const float ya  = ma[p * 2 + 1] * inv_level;
    const float ubx = mb[p * 2 + 0] * inv_level;
    const float uby = mb[p * 2 + 1] * inv_level;
    const float xs  = 2.0f * noise[p * 2 + 0] - 1.0f + ubx;
    const float ys  = 2.0f * noise[p * 2 + 1] - 1.0f + uby;

    // ---- F_a bilinear indices (interior guaranteed; clamp for safety) ----
    const float ax0f = floorf(xa), ay0f = floorf(ya);
    const float awx = xa - ax0f, awy = ya - ay0f;
    const int ax0 = min(max((int)ax0f, 0), W_ - 2);
    const int ay0 = min(max((int)ay0f, 0), H_ - 2);

    // ---- F_b patch indices (interior guaranteed: x0 in [1,W-3], y0 in [1,H-3]) ----
    const float bx0f = floorf(xs), by0f = floorf(ys);
    const float wx = xs - bx0f, wy = ys - by0f;
    const int x0 = min(max((int)bx0f, 1), W_ - 3);
    const int y0 = min(max((int)by0f, 1), H_ - 3);
    const int xm = x0 - 1;                   // row vector start: xm..x0+2 (4 floats)
    const int ym = y0 - 1;
    const int y1 = y0 + 1;
    const int yp = y0 + 2;

    const int o_y0 = y0 * W_ + xm;           // 4-float row at y0
    const int o_y1 = y1 * W_ + xm;           // 4-float row at y1
    const int o_ym = ym * W_ + x0;           // 2-float row at ym
    const int o_yp = yp * W_ + x0;           // 2-float row at yp
    const int o_a0 = ay0 * W_ + ax0;         // 2-float row at ay0
    const int o_a1 = (ay0 + 1) * W_ + ax0;   // 2-float row at ay1

    // channel planes: c0 = lane, c1 = lane + 64
    const size_t plane = ((size_t)b * C_ + lane) * HW_;
    const float* __restrict__ fa0 = Fa + plane;
    const float* __restrict__ fa1 = fa0 + (size_t)64 * HW_;
    const float* __restrict__ fb0 = Fb + plane;
    const float* __restrict__ fb1 = fb0 + (size_t)64 * HW_;

    // ---------- 12 independent vector gathers (64B/lane/channel-pair) ----------
    const f4 row0_0 = load4(fb0 + o_y0);
    const f4 row1_0 = load4(fb0 + o_y1);
    const f2 rm_0   = load2(fb0 + o_ym);
    const f2 rp_0   = load2(fb0 + o_yp);
    const f2 a0_0   = load2(fa0 + o_a0);
    const f2 a1_0   = load2(fa0 + o_a1);

    const f4 row0_1 = load4(fb1 + o_y0);
    const f4 row1_1 = load4(fb1 + o_y1);
    const f2 rm_1   = load2(fb1 + o_ym);
    const f2 rp_1   = load2(fb1 + o_yp);
    const f2 a0_1   = load2(fa1 + o_a0);
    const f2 a1_1   = load2(fa1 + o_a1);

    // ---------- weights ----------
    const float aw00 = (1.f - awx) * (1.f - awy);
    const float aw01 = awx * (1.f - awy);
    const float aw10 = (1.f - awx) * awy;
    const float aw11 = awx * awy;
    const float w00 = (1.f - wx) * (1.f - wy);
    const float w01 = wx * (1.f - wy);
    const float w10 = (1.f - wx) * wy;
    const float w11 = wx * wy;

    float vals[9];
    #pragma unroll
    for (int k = 0; k < 9; ++k) vals[k] = 0.f;

    #pragma unroll
    for (int ch = 0; ch < 2; ++ch) {
        const f4 row0 = ch ? row0_1 : row0_0;
        const f4 row1 = ch ? row1_1 : row1_0;
        const f2 rm   = ch ? rm_1   : rm_0;
        const f2 rp   = ch ? rp_1   : rp_0;
        const f2 a0   = ch ? a0_1   : a0_0;
        const f2 a1   = ch ? a1_1   : a1_0;

        const float ft = a0.x * aw00 + a0.y * aw01 + a1.x * aw10 + a1.y * aw11;
        const float fs = row0.y * w00 + row0.z * w01 + row1.y * w10 + row1.z * w11;
        const float jx = 0.5f * ((row0.z - row0.x) * w00 + (row0.w - row0.y) * w01
                               + (row1.z - row1.x) * w10 + (row1.w - row1.y) * w11);
        const float jy = 0.5f * ((row1.y - rm.x) * w00 + (row1.z - rm.y) * w01
                               + (rp.x - row0.y) * w10 + (rp.y - row0.z) * w11);

        vals[0] += ft * ft;
        vals[1] += fs * fs;
        vals[2] += jx * fs;
        vals[3] += jx * ft;
        vals[4] += jy * fs;
        vals[5] += jy * ft;
        vals[6] += jx * jx;
        vals[7] += jx * jy;
        vals[8] += jy * jy;
    }

    // ---------- 9 wave reductions (no LDS, no barrier) ----------
    #pragma unroll
    for (int k = 0; k < 9; ++k)
        vals[k] = wave_reduce(vals[k]);

    if (lane == 0) {
        const float nt = fmaxf(sqrtf(vals[0]), 1e-12f);
        const float ns = fmaxf(sqrtf(vals[1]), 1e-12f);
        const float b0 = vals[2] / ns - vals[3] / nt;
        const float b1 = vals[4] / ns - vals[5] / nt;
        const float H00 = vals[6] + 1e-9f;
        const float H01 = vals[7];
        const float H11 = vals[8] + 1e-9f;
        const float det = H00 * H11 - H01 * H01;
        const float inv = 1.0f / det;
        const float u0 = (H11 * b0 - H01 * b1) * inv;   // (Hinv @ b)[0]
        const float u1 = (H00 * b1 - H01 * b0) * inv;   // (Hinv @ b)[1]
        const float d0 = (ubx - xs) + u0;               // diff = ub - miu
        const float d1 = (uby - ys) + u1;
        const float quad = d0 * (H00 * d0 + H01 * d1) + d1 * (H01 * d0 + H11 * d1);
        ws_e1[p] = 0.5f * quad;
        ws_ld[p] = logf(det);
    }
}

// Single-block deterministic reduction of the 4096 per-point partials.
__global__ __launch_bounds__(256) void gn_reduce_kernel(
    const float* __restrict__ ws_e1, const float* __restrict__ ws_ld,
    float* __restrict__ out)
{
    __shared__ double sm1[256];
    __shared__ double sm2[256];
    double a1 = 0.0, a2 = 0.0;
    for (int i = threadIdx.x; i < NPTS; i += 256) {
        a1 += (double)ws_e1[i];
        a2 += (double)ws_ld[i];
    }
    sm1[threadIdx.x] = a1;
    sm2[threadIdx.x] = a2;
    __syncthreads();
    for (int s = 128; s > 0; s >>= 1) {
        if (threadIdx.x < s) {
            sm1[threadIdx.x] += sm1[threadIdx.x + s];
            sm2[threadIdx.x] += sm2[threadIdx.x + s];
        }
        __syncthreads();
    }
    if (threadIdx.x == 0) {
        const double e1 = sm1[0];
        const double sum_ld = sm2[0];
        const double log2pi = (double)logf(6.283185307179586f);
        const double e2 = (double)NPTS * log2pi - 0.5 * sum_ld;
        const double e = 1.0 * e1 + (2.0 / 7.0) * e2;   // E1_LAMDA=1, E2_LAMDA=2/7
        out[0] = (float)(0.3 * e);                      // GN_LAMDA * e
        out[1] = (float)e1;
        out[2] = (float)e2;
    }
}

extern "C" void kernel_launch(void* const* d_in, const int* in_sizes, int n_in,
                              void* d_out, int out_size, void* d_ws, size_t ws_size,
                              hipStream_t stream) {
    const float* Fa    = (const float*)d_in[0];
    const float* Fb    = (const float*)d_in[1];
    const float* ma    = (const float*)d_in[2];
    const float* mb    = (const float*)d_in[3];
    const float* noise = (const float*)d_in[4];
    float* out = (float*)d_out;

    float* ws_e1 = (float*)d_ws;          // 4096 floats
    float* ws_ld = ws_e1 + NPTS;          // 4096 floats

    gn_point_kernel<<<NPTS / 4, 256, 0, stream>>>(Fa, Fb, ma, mb, noise, ws_e1, ws_ld);
    gn_reduce_kernel<<<1, 256, 0, stream>>>(ws_e1, ws_ld, out);
}